// Round 1
// baseline (1935.646 us; speedup 1.0000x reference)
//
#include <hip/hip_runtime.h>

// ---------------------------------------------------------------------------
// MambaConvBlock fused pipeline, fp32 correctness-first baseline.
// Sizes (fixed): B=8, CIN=64, COUT=128, H=W=64, L=4096, T=32768,
//                DINNER=256, DSTATE=16, DTRANK=8, DCONV=4.
// ---------------------------------------------------------------------------

#define DEV __device__ __forceinline__

DEV float siluf(float v) { return v / (1.f + __expf(-v)); }

// ---------------- conv3x3 + BN + ReLU (direct, LDS-tiled) -------------------
// Block: 256 threads = 16x16 spatial tile; computes 32 output channels.
// Grid: (16 tiles, 4 co-groups, 8 batch).
template<int CI, int SEQ_OUT>
__global__ __launch_bounds__(256) void conv_bn_relu(
    const float* __restrict__ X,   // (B, CI, 64, 64)
    const float* __restrict__ Wc,  // (128, CI, 3, 3)
    const float* __restrict__ bc,
    const float* __restrict__ bg, const float* __restrict__ bb,
    const float* __restrict__ bm, const float* __restrict__ bv,
    float* __restrict__ Y)         // SEQ_OUT? (B,4096,128) : (B,128,64,64)
{
  __shared__ float xs[16][18][18];     // [ci][y][x], x fastest -> conflict-free
  __shared__ float wsh[16 * 9 * 32];   // [ci][tap][co], co fastest (float4 bcast)
  const int tid = threadIdx.x;
  const int tile = blockIdx.x;
  const int cog  = blockIdx.y;
  const int b    = blockIdx.z;
  const int tx0 = (tile & 3) * 16, ty0 = (tile >> 2) * 16;
  const int px = tid & 15, py = tid >> 4;

  float acc[32];
  #pragma unroll
  for (int i = 0; i < 32; ++i) acc[i] = 0.f;

  for (int c0 = 0; c0 < CI; c0 += 16) {
    // stage input tile (with halo, zero-padded at image edges)
    for (int e = tid; e < 16 * 18 * 18; e += 256) {
      int ci = e / 324, rem = e % 324;
      int yy = rem / 18, xx = rem % 18;
      int gy = ty0 + yy - 1, gx = tx0 + xx - 1;
      float val = 0.f;
      if (gy >= 0 && gy < 64 && gx >= 0 && gx < 64)
        val = X[(((size_t)b * CI + c0 + ci) * 64 + gy) * 64 + gx];
      xs[ci][yy][xx] = val;
    }
    // stage weights for this (co-group, ci-chunk)
    for (int e = tid; e < 16 * 9 * 32; e += 256) {
      int ci = e / 288, rem = e % 288;
      int tap = rem >> 5, co = rem & 31;
      wsh[e] = Wc[((size_t)(cog * 32 + co) * CI + c0 + ci) * 9 + tap];
    }
    __syncthreads();

    #pragma unroll 2
    for (int ci = 0; ci < 16; ++ci) {
      float xv[9];
      #pragma unroll
      for (int t = 0; t < 9; ++t)
        xv[t] = xs[ci][py + t / 3][px + t % 3];
      const float4* wrow = reinterpret_cast<const float4*>(&wsh[ci * 288]);
      #pragma unroll
      for (int t = 0; t < 9; ++t) {
        #pragma unroll
        for (int c4 = 0; c4 < 8; ++c4) {
          float4 w4 = wrow[t * 8 + c4];
          acc[c4 * 4 + 0] = fmaf(w4.x, xv[t], acc[c4 * 4 + 0]);
          acc[c4 * 4 + 1] = fmaf(w4.y, xv[t], acc[c4 * 4 + 1]);
          acc[c4 * 4 + 2] = fmaf(w4.z, xv[t], acc[c4 * 4 + 2]);
          acc[c4 * 4 + 3] = fmaf(w4.w, xv[t], acc[c4 * 4 + 3]);
        }
      }
    }
    __syncthreads();
  }

  const int gy = ty0 + py, gx = tx0 + px;
  float outv[32];
  #pragma unroll
  for (int co = 0; co < 32; ++co) {
    int cg = cog * 32 + co;
    float a = bg[cg] * rsqrtf(bv[cg] + 1e-5f);
    float r = (acc[co] + bc[cg] - bm[cg]) * a + bb[cg];
    outv[co] = fmaxf(r, 0.f);
  }
  if (SEQ_OUT) {
    size_t base = ((size_t)b * 4096 + gy * 64 + gx) * 128 + cog * 32;
    #pragma unroll
    for (int c4 = 0; c4 < 8; ++c4) {
      float4 o;
      o.x = outv[c4 * 4 + 0]; o.y = outv[c4 * 4 + 1];
      o.z = outv[c4 * 4 + 2]; o.w = outv[c4 * 4 + 3];
      *reinterpret_cast<float4*>(&Y[base + c4 * 4]) = o;
    }
  } else {
    #pragma unroll
    for (int co = 0; co < 32; ++co)
      Y[(((size_t)b * 128 + cog * 32 + co) * 64 + gy) * 64 + gx] = outv[co];
  }
}

// ---------------- generic fp32 GEMM: C[M,N] = A[M,K] @ W[N,K]^T -------------
// Block 256 threads -> 64x64 C-tile, 4x4 per thread, BK=16.
__global__ __launch_bounds__(256) void gemm_nt(
    const float* __restrict__ A, const float* __restrict__ W,
    float* __restrict__ C, int M, int N, int K)
{
  __shared__ float As[16][68];   // [k][m], 68-pad: 16B-aligned rows, no conflicts
  __shared__ float Bs[16][68];   // [k][n]
  const int m0 = blockIdx.x * 64, n0 = blockIdx.y * 64;
  const int tid = threadIdx.x;
  const int tx = tid & 15, ty = tid >> 4;
  const int lr = tid >> 2;            // 0..63
  const int lk = (tid & 3) * 4;       // 0,4,8,12
  float acc[4][4] = {};

  for (int k0 = 0; k0 < K; k0 += 16) {
    float4 av = *reinterpret_cast<const float4*>(&A[(size_t)(m0 + lr) * K + k0 + lk]);
    float4 wv = make_float4(0.f, 0.f, 0.f, 0.f);
    if (n0 + lr < N)
      wv = *reinterpret_cast<const float4*>(&W[(size_t)(n0 + lr) * K + k0 + lk]);
    As[lk + 0][lr] = av.x; As[lk + 1][lr] = av.y;
    As[lk + 2][lr] = av.z; As[lk + 3][lr] = av.w;
    Bs[lk + 0][lr] = wv.x; Bs[lk + 1][lr] = wv.y;
    Bs[lk + 2][lr] = wv.z; Bs[lk + 3][lr] = wv.w;
    __syncthreads();
    #pragma unroll
    for (int k = 0; k < 16; ++k) {
      float4 a4 = *reinterpret_cast<const float4*>(&As[k][ty * 4]);
      float4 b4 = *reinterpret_cast<const float4*>(&Bs[k][tx * 4]);
      float avv[4] = {a4.x, a4.y, a4.z, a4.w};
      float bvv[4] = {b4.x, b4.y, b4.z, b4.w};
      #pragma unroll
      for (int i = 0; i < 4; ++i)
        #pragma unroll
        for (int j = 0; j < 4; ++j)
          acc[i][j] = fmaf(avv[i], bvv[j], acc[i][j]);
    }
    __syncthreads();
  }
  #pragma unroll
  for (int i = 0; i < 4; ++i) {
    int m = m0 + ty * 4 + i;
    #pragma unroll
    for (int j = 0; j < 4; ++j) {
      int n = n0 + tx * 4 + j;
      if (n < N) C[(size_t)m * N + n] = acc[i][j];
    }
  }
}

// ---------------- depthwise causal conv1d (DCONV=4) + silu ------------------
__global__ void conv1d_silu(const float* __restrict__ xm,   // (T,256)
                            const float* __restrict__ w,    // (256,4)
                            const float* __restrict__ bias, // (256)
                            float* __restrict__ out)        // (T,256)
{
  const int total = 8 * 4096 * 256;
  for (int idx = blockIdx.x * blockDim.x + threadIdx.x; idx < total;
       idx += gridDim.x * blockDim.x) {
    int d = idx & 255;
    int t = idx >> 8;
    int l = t & 4095;
    float acc = bias[d];
    #pragma unroll
    for (int j = 0; j < 4; ++j) {
      int ll = l - 3 + j;
      if (ll >= 0)
        acc = fmaf(xm[(size_t)(t - 3 + j) * 256 + d], w[d * 4 + j], acc);
    }
    out[idx] = siluf(acc);
  }
}

// ---------------- dt = softplus(dt_r @ dtw^T + dtb) -------------------------
__global__ void dt_kernel(const float* __restrict__ xdb,  // (T,40), dt_r = [:8]
                          const float* __restrict__ dtw,  // (256,8)
                          const float* __restrict__ dtb,  // (256)
                          float* __restrict__ out)        // (T,256)
{
  const int total = 8 * 4096 * 256;
  for (int idx = blockIdx.x * blockDim.x + threadIdx.x; idx < total;
       idx += gridDim.x * blockDim.x) {
    int d = idx & 255;
    int t = idx >> 8;
    float acc = dtb[d];
    const float* xr = &xdb[(size_t)t * 40];
    #pragma unroll
    for (int r = 0; r < 8; ++r) acc = fmaf(xr[r], dtw[d * 8 + r], acc);
    out[idx] = (acc > 20.f) ? acc : log1pf(__expf(acc));
  }
}

// ---------------- selective scan + D*x + silu(z) gating ---------------------
// Block = 64 threads = 4 d-channels x 16 states. Grid = 8b x 64 dgroups = 512.
// y written in-place over x_ssm (read-before-write within same wave iter).
__global__ __launch_bounds__(64) void scan_kernel(
    const float* __restrict__ dtbuf, float* __restrict__ xssm,
    const float* __restrict__ xdb, const float* __restrict__ zb,
    const float* __restrict__ A_log, const float* __restrict__ Dp)
{
  const int blk = blockIdx.x;
  const int b = blk >> 6, dg = blk & 63;
  const int tid = threadIdx.x;
  const int s = tid & 15, dl = tid >> 4;
  const int d = dg * 4 + dl;
  const float Aneg = -expf(A_log[d * 16 + s]);
  const float Dd = Dp[d];
  const size_t base_td = (size_t)b * 4096 * 256 + d;
  const size_t base_bc = (size_t)b * 4096 * 40;
  float h = 0.f;
  float dtv = dtbuf[base_td], xv = xssm[base_td];
  float Bv = xdb[base_bc + 8 + s], Cv = xdb[base_bc + 24 + s];
  float zv = zb[base_td];
  for (int l = 0; l < 4096; ++l) {
    float dtn = 0.f, xn = 0.f, Bn = 0.f, Cn = 0.f, zn = 0.f;
    if (l + 1 < 4096) {
      size_t o = base_td + (size_t)(l + 1) * 256;
      dtn = dtbuf[o]; xn = xssm[o]; zn = zb[o];
      size_t o2 = base_bc + (size_t)(l + 1) * 40;
      Bn = xdb[o2 + 8 + s]; Cn = xdb[o2 + 24 + s];
    }
    float dA = __expf(dtv * Aneg);
    h = fmaf(dA, h, dtv * xv * Bv);
    float p = h * Cv;
    p += __shfl_xor(p, 1);
    p += __shfl_xor(p, 2);
    p += __shfl_xor(p, 4);
    p += __shfl_xor(p, 8);
    if (s == 0) {
      float yg = (p + Dd * xv) * siluf(zv);
      xssm[base_td + (size_t)l * 256] = yg;
    }
    dtv = dtn; xv = xn; Bv = Bn; Cv = Cn; zv = zn;
  }
}

// ---------------- LayerNorm(128) + transpose to NCHW ------------------------
// Block 256 threads handles 64 tokens (same batch).
__global__ __launch_bounds__(256) void ln_transpose(
    const float* __restrict__ X,  // (T,128)
    const float* __restrict__ g, const float* __restrict__ b,
    float* __restrict__ out)      // (8,128,64,64)
{
  __shared__ float buf[64][129];
  const int t0 = blockIdx.x * 64;
  const int bb = t0 >> 12, l0 = t0 & 4095;
  const int tid = threadIdx.x;
  for (int idx = tid; idx < 64 * 128; idx += 256)
    buf[idx >> 7][idx & 127] = X[(size_t)t0 * 128 + idx];
  __syncthreads();
  const int tt = tid >> 2, q = tid & 3;
  float s = 0.f, sq = 0.f;
  #pragma unroll
  for (int i = 0; i < 32; ++i) {
    float v = buf[tt][q * 32 + i];
    s += v; sq += v * v;
  }
  s  += __shfl_xor(s, 1);  s  += __shfl_xor(s, 2);
  sq += __shfl_xor(sq, 1); sq += __shfl_xor(sq, 2);
  float mu = s * (1.f / 128.f);
  float var = sq * (1.f / 128.f) - mu * mu;
  float rstd = rsqrtf(fmaxf(var, 0.f) + 1e-5f);
  #pragma unroll
  for (int i = 0; i < 32; ++i) {
    int c = q * 32 + i;
    buf[tt][c] = (buf[tt][c] - mu) * rstd * g[c] + b[c];
  }
  __syncthreads();
  for (int idx = tid; idx < 64 * 128; idx += 256) {
    int c = idx >> 6, t2 = idx & 63;
    out[((size_t)bb * 128 + c) * 4096 + l0 + t2] = buf[t2][c];
  }
}

// ---------------------------------------------------------------------------
extern "C" void kernel_launch(void* const* d_in, const int* in_sizes, int n_in,
                              void* d_out, int out_size, void* d_ws, size_t ws_size,
                              hipStream_t stream) {
  const float* x        = (const float*)d_in[0];
  const float* conv1_w  = (const float*)d_in[1];
  const float* conv1_b  = (const float*)d_in[2];
  const float* bn1_g    = (const float*)d_in[3];
  const float* bn1_b    = (const float*)d_in[4];
  const float* bn1_m    = (const float*)d_in[5];
  const float* bn1_v    = (const float*)d_in[6];
  const float* conv2_w  = (const float*)d_in[7];
  const float* conv2_b  = (const float*)d_in[8];
  const float* bn2_g    = (const float*)d_in[9];
  const float* bn2_b    = (const float*)d_in[10];
  const float* bn2_m    = (const float*)d_in[11];
  const float* bn2_v    = (const float*)d_in[12];
  const float* in_proj_w  = (const float*)d_in[13];  // (512,128)
  const float* conv1d_w   = (const float*)d_in[14];  // (256,1,4)
  const float* conv1d_b   = (const float*)d_in[15];
  const float* x_proj_w   = (const float*)d_in[16];  // (40,256)
  const float* dt_proj_w  = (const float*)d_in[17];  // (256,8)
  const float* dt_proj_b  = (const float*)d_in[18];
  const float* A_log      = (const float*)d_in[19];  // (256,16)
  const float* Dp         = (const float*)d_in[20];  // (256)
  const float* out_proj_w = (const float*)d_in[21];  // (128,256)
  const float* ln_g       = (const float*)d_in[22];
  const float* ln_b       = (const float*)d_in[23];
  float* out = (float*)d_out;

  float* ws = (float*)d_ws;
  // workspace layout (floats), with lifetime-based reuse; total 27,136,544 f
  float* h1   = ws;              // [0,        4194304)
  float* seq  = ws + 4194304;    // [4194304,  8388608)
  float* xm   = ws + 8388608;    // [8388608,  16777216)
  float* zb   = ws + 16777216;   // [16777216, 25165824)
  float* xssm = ws;              // [0,        8388608)   reuse h1+seq
  float* xdb  = ws + 25165824;   // [25165824, 27136544)
  float* dtb  = ws + 8388608;    // reuse xm after conv1d
  float* outs = ws + 16777216;   // reuse zb after scan

  // 1. conv1 + bn1 + relu -> h1 (NCHW)
  conv_bn_relu<64, 0><<<dim3(16, 4, 8), 256, 0, stream>>>(
      x, conv1_w, conv1_b, bn1_g, bn1_b, bn1_m, bn1_v, h1);
  // 2. conv2 + bn2 + relu -> seq (B,L,128)
  conv_bn_relu<128, 1><<<dim3(16, 4, 8), 256, 0, stream>>>(
      h1, conv2_w, conv2_b, bn2_g, bn2_b, bn2_m, bn2_v, seq);
  // 3. in_proj: xm = seq @ W[0:256]^T ; z = seq @ W[256:512]^T
  gemm_nt<<<dim3(512, 4), 256, 0, stream>>>(seq, in_proj_w, xm, 32768, 256, 128);
  gemm_nt<<<dim3(512, 4), 256, 0, stream>>>(seq, in_proj_w + 256 * 128, zb,
                                            32768, 256, 128);
  // 4. depthwise causal conv1d + silu -> x_ssm
  conv1d_silu<<<4096, 256, 0, stream>>>(xm, conv1d_w, conv1d_b, xssm);
  // 5. x_proj -> xdb (T,40)
  gemm_nt<<<dim3(512, 1), 256, 0, stream>>>(xssm, x_proj_w, xdb, 32768, 40, 256);
  // 6. dt = softplus(dt_r @ dtw^T + dtb) -> dtb (T,256)
  dt_kernel<<<4096, 256, 0, stream>>>(xdb, dt_proj_w, dt_proj_b, dtb);
  // 7. selective scan (+ D*x, silu(z) gate), y in-place over x_ssm
  scan_kernel<<<512, 64, 0, stream>>>(dtb, xssm, xdb, zb, A_log, Dp);
  // 8. out_proj -> outs (T,128)
  gemm_nt<<<dim3(512, 2), 256, 0, stream>>>(xssm, out_proj_w, outs, 32768, 128, 256);
  // 9. LayerNorm + NCHW transpose -> out
  ln_transpose<<<512, 256, 0, stream>>>(outs, ln_g, ln_b, out);
}

// Round 2
// 678.335 us; speedup vs baseline: 2.8535x; 2.8535x over previous
//
#include <hip/hip_runtime.h>

// ---------------------------------------------------------------------------
// MambaConvBlock fused pipeline. Round 2: chunked parallel scan.
// Sizes (fixed): B=8, CIN=64, COUT=128, H=W=64, L=4096, T=32768,
//                DINNER=256, DSTATE=16, DTRANK=8, DCONV=4.
// ---------------------------------------------------------------------------

#define DEV __device__ __forceinline__

DEV float siluf(float v) { return v / (1.f + __expf(-v)); }

constexpr int NC = 64;   // chunks per batch
constexpr int CL = 64;   // chunk length (NC*CL = 4096)

// ---------------- conv3x3 + BN + ReLU (direct, LDS-tiled) -------------------
template<int CI, int SEQ_OUT>
__global__ __launch_bounds__(256) void conv_bn_relu(
    const float* __restrict__ X,
    const float* __restrict__ Wc,
    const float* __restrict__ bc,
    const float* __restrict__ bg, const float* __restrict__ bb,
    const float* __restrict__ bm, const float* __restrict__ bv,
    float* __restrict__ Y)
{
  __shared__ float xs[16][18][18];
  __shared__ float wsh[16 * 9 * 32];
  const int tid = threadIdx.x;
  const int tile = blockIdx.x;
  const int cog  = blockIdx.y;
  const int b    = blockIdx.z;
  const int tx0 = (tile & 3) * 16, ty0 = (tile >> 2) * 16;
  const int px = tid & 15, py = tid >> 4;

  float acc[32];
  #pragma unroll
  for (int i = 0; i < 32; ++i) acc[i] = 0.f;

  for (int c0 = 0; c0 < CI; c0 += 16) {
    for (int e = tid; e < 16 * 18 * 18; e += 256) {
      int ci = e / 324, rem = e % 324;
      int yy = rem / 18, xx = rem % 18;
      int gy = ty0 + yy - 1, gx = tx0 + xx - 1;
      float val = 0.f;
      if (gy >= 0 && gy < 64 && gx >= 0 && gx < 64)
        val = X[(((size_t)b * CI + c0 + ci) * 64 + gy) * 64 + gx];
      xs[ci][yy][xx] = val;
    }
    for (int e = tid; e < 16 * 9 * 32; e += 256) {
      int ci = e / 288, rem = e % 288;
      int tap = rem >> 5, co = rem & 31;
      wsh[e] = Wc[((size_t)(cog * 32 + co) * CI + c0 + ci) * 9 + tap];
    }
    __syncthreads();

    #pragma unroll 2
    for (int ci = 0; ci < 16; ++ci) {
      float xv[9];
      #pragma unroll
      for (int t = 0; t < 9; ++t)
        xv[t] = xs[ci][py + t / 3][px + t % 3];
      const float4* wrow = reinterpret_cast<const float4*>(&wsh[ci * 288]);
      #pragma unroll
      for (int t = 0; t < 9; ++t) {
        #pragma unroll
        for (int c4 = 0; c4 < 8; ++c4) {
          float4 w4 = wrow[t * 8 + c4];
          acc[c4 * 4 + 0] = fmaf(w4.x, xv[t], acc[c4 * 4 + 0]);
          acc[c4 * 4 + 1] = fmaf(w4.y, xv[t], acc[c4 * 4 + 1]);
          acc[c4 * 4 + 2] = fmaf(w4.z, xv[t], acc[c4 * 4 + 2]);
          acc[c4 * 4 + 3] = fmaf(w4.w, xv[t], acc[c4 * 4 + 3]);
        }
      }
    }
    __syncthreads();
  }

  const int gy = ty0 + py, gx = tx0 + px;
  float outv[32];
  #pragma unroll
  for (int co = 0; co < 32; ++co) {
    int cg = cog * 32 + co;
    float a = bg[cg] * rsqrtf(bv[cg] + 1e-5f);
    float r = (acc[co] + bc[cg] - bm[cg]) * a + bb[cg];
    outv[co] = fmaxf(r, 0.f);
  }
  if (SEQ_OUT) {
    size_t base = ((size_t)b * 4096 + gy * 64 + gx) * 128 + cog * 32;
    #pragma unroll
    for (int c4 = 0; c4 < 8; ++c4) {
      float4 o;
      o.x = outv[c4 * 4 + 0]; o.y = outv[c4 * 4 + 1];
      o.z = outv[c4 * 4 + 2]; o.w = outv[c4 * 4 + 3];
      *reinterpret_cast<float4*>(&Y[base + c4 * 4]) = o;
    }
  } else {
    #pragma unroll
    for (int co = 0; co < 32; ++co)
      Y[(((size_t)b * 128 + cog * 32 + co) * 64 + gy) * 64 + gx] = outv[co];
  }
}

// ---------------- generic fp32 GEMM: C[M,N] = A[M,K] @ W[N,K]^T -------------
__global__ __launch_bounds__(256) void gemm_nt(
    const float* __restrict__ A, const float* __restrict__ W,
    float* __restrict__ C, int M, int N, int K)
{
  __shared__ float As[16][68];
  __shared__ float Bs[16][68];
  const int m0 = blockIdx.x * 64, n0 = blockIdx.y * 64;
  const int tid = threadIdx.x;
  const int tx = tid & 15, ty = tid >> 4;
  const int lr = tid >> 2;
  const int lk = (tid & 3) * 4;
  float acc[4][4] = {};

  for (int k0 = 0; k0 < K; k0 += 16) {
    float4 av = *reinterpret_cast<const float4*>(&A[(size_t)(m0 + lr) * K + k0 + lk]);
    float4 wv = make_float4(0.f, 0.f, 0.f, 0.f);
    if (n0 + lr < N)
      wv = *reinterpret_cast<const float4*>(&W[(size_t)(n0 + lr) * K + k0 + lk]);
    As[lk + 0][lr] = av.x; As[lk + 1][lr] = av.y;
    As[lk + 2][lr] = av.z; As[lk + 3][lr] = av.w;
    Bs[lk + 0][lr] = wv.x; Bs[lk + 1][lr] = wv.y;
    Bs[lk + 2][lr] = wv.z; Bs[lk + 3][lr] = wv.w;
    __syncthreads();
    #pragma unroll
    for (int k = 0; k < 16; ++k) {
      float4 a4 = *reinterpret_cast<const float4*>(&As[k][ty * 4]);
      float4 b4 = *reinterpret_cast<const float4*>(&Bs[k][tx * 4]);
      float avv[4] = {a4.x, a4.y, a4.z, a4.w};
      float bvv[4] = {b4.x, b4.y, b4.z, b4.w};
      #pragma unroll
      for (int i = 0; i < 4; ++i)
        #pragma unroll
        for (int j = 0; j < 4; ++j)
          acc[i][j] = fmaf(avv[i], bvv[j], acc[i][j]);
    }
    __syncthreads();
  }
  #pragma unroll
  for (int i = 0; i < 4; ++i) {
    int m = m0 + ty * 4 + i;
    #pragma unroll
    for (int j = 0; j < 4; ++j) {
      int n = n0 + tx * 4 + j;
      if (n < N) C[(size_t)m * N + n] = acc[i][j];
    }
  }
}

// ---------------- depthwise causal conv1d (DCONV=4) + silu, float4 ----------
__global__ __launch_bounds__(256) void conv1d_silu(
    const float* __restrict__ xm,   // (T,256)
    const float* __restrict__ w,    // (256,4)
    const float* __restrict__ bias, // (256)
    float* __restrict__ out)        // (T,256)
{
  __shared__ float ws4[4][256];   // [tap][d]
  __shared__ float bsh[256];
  for (int i = threadIdx.x; i < 1024; i += 256)
    ws4[i >> 8][i & 255] = w[(i & 255) * 4 + (i >> 8)];
  bsh[threadIdx.x] = bias[threadIdx.x];
  __syncthreads();
  const int total = 8 * 4096 * 64;  // float4 units
  for (int idx = blockIdx.x * 256 + threadIdx.x; idx < total;
       idx += gridDim.x * 256) {
    int d4 = idx & 63, t = idx >> 6, l = t & 4095;
    int d = d4 * 4;
    float4 acc = *reinterpret_cast<const float4*>(&bsh[d]);
    #pragma unroll
    for (int j = 0; j < 4; ++j) {
      if (l - 3 + j >= 0) {
        float4 xv = *reinterpret_cast<const float4*>(&xm[(size_t)(t - 3 + j) * 256 + d]);
        float4 wv = *reinterpret_cast<const float4*>(&ws4[j][d]);
        acc.x = fmaf(xv.x, wv.x, acc.x);
        acc.y = fmaf(xv.y, wv.y, acc.y);
        acc.z = fmaf(xv.z, wv.z, acc.z);
        acc.w = fmaf(xv.w, wv.w, acc.w);
      }
    }
    acc.x = siluf(acc.x); acc.y = siluf(acc.y);
    acc.z = siluf(acc.z); acc.w = siluf(acc.w);
    *reinterpret_cast<float4*>(&out[(size_t)t * 256 + d]) = acc;
  }
}

// ---------------- chunked selective scan ------------------------------------
// Pass 1: per (b, chunk), thread d holds h[16]; computes Q (end state from 0)
//         and S = sum(dt) over chunk. dt_proj+softplus fused (xdb staged LDS).
__global__ __launch_bounds__(256) void scan_pass1(
    const float* __restrict__ xssm, const float* __restrict__ xdb,
    const float* __restrict__ dtw, const float* __restrict__ dtb,
    const float* __restrict__ A_log,
    float* __restrict__ Q, float* __restrict__ S)
{
  __shared__ float sh[CL][40];
  const int c = blockIdx.x, b = blockIdx.y;
  const int d = threadIdx.x;
  const int l0 = c * CL;
  const float* src = &xdb[((size_t)b * 4096 + l0) * 40];
  for (int i = threadIdx.x; i < CL * 40; i += 256)
    sh[i / 40][i % 40] = src[i];

  float wdt[8];
  #pragma unroll
  for (int r = 0; r < 8; ++r) wdt[r] = dtw[d * 8 + r];
  const float bdt = dtb[d];
  float Aneg[16], h[16];
  #pragma unroll
  for (int s = 0; s < 16; ++s) {
    Aneg[s] = -__expf(A_log[d * 16 + s]);
    h[s] = 0.f;
  }
  __syncthreads();

  float sdt = 0.f;
  const size_t xbase = ((size_t)b * 4096 + l0) * 256 + d;
  float xv = xssm[xbase];
  for (int l = 0; l < CL; ++l) {
    float xn = (l + 1 < CL) ? xssm[xbase + (size_t)(l + 1) * 256] : 0.f;
    float acc = bdt;
    #pragma unroll
    for (int r = 0; r < 8; ++r) acc = fmaf(sh[l][r], wdt[r], acc);
    float dt = (acc > 20.f) ? acc : log1pf(__expf(acc));
    sdt += dt;
    float dtx = dt * xv;
    #pragma unroll
    for (int s = 0; s < 16; ++s) {
      float dA = __expf(dt * Aneg[s]);
      h[s] = fmaf(dA, h[s], dtx * sh[l][8 + s]);
    }
    xv = xn;
  }
  float* q = &Q[(((size_t)b * NC + c) * 256 + d) * 16];
  #pragma unroll
  for (int s = 0; s < 16; ++s) q[s] = h[s];
  S[((size_t)b * NC + c) * 256 + d] = sdt;
}

// Pass 2 (combine): h_start[c] = P(c-1)*h_start[c-1] + Q[c-1],
// P = exp(Aneg * S). Overwrites Q with h_start, in place.
__global__ __launch_bounds__(256) void scan_combine(
    float* __restrict__ Q, const float* __restrict__ S,
    const float* __restrict__ A_log)
{
  int g = blockIdx.x * 256 + threadIdx.x;   // 32768 total
  int b = g >> 12, d = (g >> 4) & 255, s = g & 15;
  float Aneg = -__expf(A_log[d * 16 + s]);
  float h = 0.f;
  for (int c = 0; c < NC; ++c) {
    size_t qi = (((size_t)b * NC + c) * 256 + d) * 16 + s;
    float q  = Q[qi];
    float sd = S[((size_t)b * NC + c) * 256 + d];
    Q[qi] = h;
    h = fmaf(__expf(Aneg * sd), h, q);
  }
}

// Pass 3: re-scan each chunk from h_start; y = C.h + D*x, gate silu(z),
// write in place over xssm.
__global__ __launch_bounds__(256) void scan_pass2(
    float* __restrict__ xssm, const float* __restrict__ xdb,
    const float* __restrict__ zb,
    const float* __restrict__ dtw, const float* __restrict__ dtb,
    const float* __restrict__ A_log, const float* __restrict__ Dp,
    const float* __restrict__ Hstart)
{
  __shared__ float sh[CL][40];
  const int c = blockIdx.x, b = blockIdx.y;
  const int d = threadIdx.x;
  const int l0 = c * CL;
  const float* src = &xdb[((size_t)b * 4096 + l0) * 40];
  for (int i = threadIdx.x; i < CL * 40; i += 256)
    sh[i / 40][i % 40] = src[i];

  float wdt[8];
  #pragma unroll
  for (int r = 0; r < 8; ++r) wdt[r] = dtw[d * 8 + r];
  const float bdt = dtb[d];
  const float Dd = Dp[d];
  float Aneg[16], h[16];
  const float* hs = &Hstart[(((size_t)b * NC + c) * 256 + d) * 16];
  #pragma unroll
  for (int s = 0; s < 16; ++s) {
    Aneg[s] = -__expf(A_log[d * 16 + s]);
    h[s] = hs[s];
  }
  __syncthreads();

  const size_t xbase = ((size_t)b * 4096 + l0) * 256 + d;
  float xv = xssm[xbase], zv = zb[xbase];
  for (int l = 0; l < CL; ++l) {
    float xn = 0.f, zn = 0.f;
    if (l + 1 < CL) {
      xn = xssm[xbase + (size_t)(l + 1) * 256];
      zn = zb[xbase + (size_t)(l + 1) * 256];
    }
    float acc = bdt;
    #pragma unroll
    for (int r = 0; r < 8; ++r) acc = fmaf(sh[l][r], wdt[r], acc);
    float dt = (acc > 20.f) ? acc : log1pf(__expf(acc));
    float dtx = dt * xv;
    float y = 0.f;
    #pragma unroll
    for (int s = 0; s < 16; ++s) {
      float dA = __expf(dt * Aneg[s]);
      h[s] = fmaf(dA, h[s], dtx * sh[l][8 + s]);
      y = fmaf(h[s], sh[l][24 + s], y);
    }
    y = (y + Dd * xv) * siluf(zv);
    xssm[xbase + (size_t)l * 256] = y;
    xv = xn; zv = zn;
  }
}

// ---------------- LayerNorm(128) + transpose to NCHW ------------------------
__global__ __launch_bounds__(256) void ln_transpose(
    const float* __restrict__ X,
    const float* __restrict__ g, const float* __restrict__ b,
    float* __restrict__ out)
{
  __shared__ float buf[64][129];
  const int t0 = blockIdx.x * 64;
  const int bb = t0 >> 12, l0 = t0 & 4095;
  const int tid = threadIdx.x;
  for (int idx = tid; idx < 64 * 128; idx += 256)
    buf[idx >> 7][idx & 127] = X[(size_t)t0 * 128 + idx];
  __syncthreads();
  const int tt = tid >> 2, q = tid & 3;
  float s = 0.f, sq = 0.f;
  #pragma unroll
  for (int i = 0; i < 32; ++i) {
    float v = buf[tt][q * 32 + i];
    s += v; sq += v * v;
  }
  s  += __shfl_xor(s, 1);  s  += __shfl_xor(s, 2);
  sq += __shfl_xor(sq, 1); sq += __shfl_xor(sq, 2);
  float mu = s * (1.f / 128.f);
  float var = sq * (1.f / 128.f) - mu * mu;
  float rstd = rsqrtf(fmaxf(var, 0.f) + 1e-5f);
  #pragma unroll
  for (int i = 0; i < 32; ++i) {
    int c = q * 32 + i;
    buf[tt][c] = (buf[tt][c] - mu) * rstd * g[c] + b[c];
  }
  __syncthreads();
  for (int idx = tid; idx < 64 * 128; idx += 256) {
    int c = idx >> 6, t2 = idx & 63;
    out[((size_t)bb * 128 + c) * 4096 + l0 + t2] = buf[t2][c];
  }
}

// ---------------------------------------------------------------------------
extern "C" void kernel_launch(void* const* d_in, const int* in_sizes, int n_in,
                              void* d_out, int out_size, void* d_ws, size_t ws_size,
                              hipStream_t stream) {
  const float* x        = (const float*)d_in[0];
  const float* conv1_w  = (const float*)d_in[1];
  const float* conv1_b  = (const float*)d_in[2];
  const float* bn1_g    = (const float*)d_in[3];
  const float* bn1_b    = (const float*)d_in[4];
  const float* bn1_m    = (const float*)d_in[5];
  const float* bn1_v    = (const float*)d_in[6];
  const float* conv2_w  = (const float*)d_in[7];
  const float* conv2_b  = (const float*)d_in[8];
  const float* bn2_g    = (const float*)d_in[9];
  const float* bn2_b    = (const float*)d_in[10];
  const float* bn2_m    = (const float*)d_in[11];
  const float* bn2_v    = (const float*)d_in[12];
  const float* in_proj_w  = (const float*)d_in[13];  // (512,128)
  const float* conv1d_w   = (const float*)d_in[14];  // (256,1,4)
  const float* conv1d_b   = (const float*)d_in[15];
  const float* x_proj_w   = (const float*)d_in[16];  // (40,256)
  const float* dt_proj_w  = (const float*)d_in[17];  // (256,8)
  const float* dt_proj_b  = (const float*)d_in[18];
  const float* A_log      = (const float*)d_in[19];  // (256,16)
  const float* Dp         = (const float*)d_in[20];  // (256)
  const float* out_proj_w = (const float*)d_in[21];  // (128,256)
  const float* ln_g       = (const float*)d_in[22];
  const float* ln_b       = (const float*)d_in[23];
  float* out = (float*)d_out;

  float* ws = (float*)d_ws;
  // workspace layout (floats), lifetime-based reuse; max index 26,607,616
  float* h1   = ws;              // [0,        4194304)
  float* seq  = ws + 4194304;    // [4194304,  8388608)
  float* xm   = ws + 8388608;    // [8388608,  16777216)
  float* zb   = ws + 16777216;   // [16777216, 25165824)
  float* xssm = ws;              // [0,        8388608)   reuse h1+seq
  float* xdb  = ws + 25165824;   // [25165824, 26476544)  (T*40)
  float* Qbuf = ws + 8388608;    // reuse xm after conv1d (8,388,608 f = B*NC*256*16)
  float* Sbuf = ws + 26476544;   // [26476544, 26607616)  (B*NC*256)
  float* outs = ws + 16777216;   // reuse zb after scan

  conv_bn_relu<64, 0><<<dim3(16, 4, 8), 256, 0, stream>>>(
      x, conv1_w, conv1_b, bn1_g, bn1_b, bn1_m, bn1_v, h1);
  conv_bn_relu<128, 1><<<dim3(16, 4, 8), 256, 0, stream>>>(
      h1, conv2_w, conv2_b, bn2_g, bn2_b, bn2_m, bn2_v, seq);
  gemm_nt<<<dim3(512, 4), 256, 0, stream>>>(seq, in_proj_w, xm, 32768, 256, 128);
  gemm_nt<<<dim3(512, 4), 256, 0, stream>>>(seq, in_proj_w + 256 * 128, zb,
                                            32768, 256, 128);
  conv1d_silu<<<2048, 256, 0, stream>>>(xm, conv1d_w, conv1d_b, xssm);
  gemm_nt<<<dim3(512, 1), 256, 0, stream>>>(xssm, x_proj_w, xdb, 32768, 40, 256);
  scan_pass1<<<dim3(NC, 8), 256, 0, stream>>>(
      xssm, xdb, dt_proj_w, dt_proj_b, A_log, Qbuf, Sbuf);
  scan_combine<<<128, 256, 0, stream>>>(Qbuf, Sbuf, A_log);
  scan_pass2<<<dim3(NC, 8), 256, 0, stream>>>(
      xssm, xdb, zb, dt_proj_w, dt_proj_b, A_log, Dp, Qbuf);
  gemm_nt<<<dim3(512, 2), 256, 0, stream>>>(xssm, out_proj_w, outs, 32768, 128, 256);
  ln_transpose<<<512, 256, 0, stream>>>(outs, ln_g, ln_b, out);
}

// Round 3
// 317.334 us; speedup vs baseline: 6.0997x; 2.1376x over previous
//
#include <hip/hip_runtime.h>
#include <hip/hip_bf16.h>

// ---------------------------------------------------------------------------
// MambaConvBlock fused pipeline. Round 3: bf16 MFMA convs + GEMMs.
// Sizes (fixed): B=8, CIN=64, COUT=128, H=W=64, L=4096, T=32768,
//                DINNER=256, DSTATE=16, DTRANK=8, DCONV=4.
// ---------------------------------------------------------------------------

typedef __attribute__((ext_vector_type(8))) short bf16x8;
typedef __attribute__((ext_vector_type(4))) float f32x4;

#define DEV __device__ __forceinline__

DEV float siluf(float v) { return v / (1.f + __expf(-v)); }

DEV unsigned short f2bf(float f) {
  __hip_bfloat16 h = __float2bfloat16(f);
  return *reinterpret_cast<unsigned short*>(&h);
}

constexpr int NC = 64;   // chunks per batch
constexpr int CL = 64;   // chunk length

// ---------------- pre-pass: NCHW fp32 -> NHWC bf16 --------------------------
__global__ __launch_bounds__(256) void nchw2nhwc_bf16(
    const float* __restrict__ X, unsigned short* __restrict__ Xb)
{
  __shared__ float t[64][65];
  const int by = blockIdx.x;            // b*64 + y
  const int b = by >> 6, y = by & 63;
  const int tid = threadIdx.x;
  for (int i = tid; i < 4096; i += 256) {
    int c = i >> 6, xx = i & 63;
    t[c][xx] = X[(((size_t)b * 64 + c) * 64 + y) * 64 + xx];
  }
  __syncthreads();
  for (int i = tid; i < 4096; i += 256) {
    int xx = i >> 6, c = i & 63;
    Xb[(((size_t)b * 64 + y) * 64 + xx) * 64 + c] = f2bf(t[c][xx]);
  }
}

// ---------------- pre-pass: conv weights -> bf16 [co][tap][ci] --------------
template<int CI>
__global__ void convw_prep(const float* __restrict__ W,
                           unsigned short* __restrict__ Wb)
{
  int idx = blockIdx.x * 256 + threadIdx.x;
  if (idx >= 128 * 9 * CI) return;
  int co = idx / (9 * CI), r = idx % (9 * CI);
  int t = r / CI, ci = r % CI;
  Wb[idx] = f2bf(W[((size_t)co * CI + ci) * 9 + t]);
}

__global__ void f32_to_bf16(const float* __restrict__ A,
                            unsigned short* __restrict__ B, int n)
{
  int i = blockIdx.x * 256 + threadIdx.x;
  if (i < n) B[i] = f2bf(A[i]);
}

// ---------------- conv3x3 + BN + ReLU as implicit-GEMM MFMA -----------------
// Block: 4 waves, all on one image row y (M=64 tokens); wave n0 = wid*32.
// A-fragments straight from L2 (NHWC bf16), B from prepped weights.
template<int CI>
__global__ __launch_bounds__(256) void conv_mfma(
    const unsigned short* __restrict__ Xb,   // [b][64][64][CI] bf16
    const unsigned short* __restrict__ Wb,   // [128][9][CI]    bf16
    const float* __restrict__ bc,
    const float* __restrict__ bg, const float* __restrict__ bb,
    const float* __restrict__ bm, const float* __restrict__ bv,
    unsigned short* __restrict__ Y)          // [b][y][x][128]  bf16 (BN+ReLU)
{
  const int lane = threadIdx.x & 63;
  const int wid  = threadIdx.x >> 6;
  const int n0 = wid * 32;
  const int y = blockIdx.x, b = blockIdx.y;
  const int lr = lane & 15, lk = (lane >> 4) * 8;

  f32x4 acc[4][2];
  #pragma unroll
  for (int i = 0; i < 4; ++i)
    #pragma unroll
    for (int j = 0; j < 2; ++j) acc[i][j] = f32x4{0.f, 0.f, 0.f, 0.f};

  #pragma unroll
  for (int dy = -1; dy <= 1; ++dy) {
    int yy = y + dy;
    if (yy < 0 || yy >= 64) continue;
    const unsigned short* arow = Xb + ((size_t)(b * 64 + yy) * 64) * CI;
    #pragma unroll
    for (int dx = -1; dx <= 1; ++dx) {
      const int tap = (dy + 1) * 3 + (dx + 1);
      #pragma unroll
      for (int kk = 0; kk < CI / 32; ++kk) {
        const int ci0 = kk * 32 + lk;
        bf16x8 bfr[2];
        #pragma unroll
        for (int nf = 0; nf < 2; ++nf)
          bfr[nf] = *reinterpret_cast<const bf16x8*>(
              Wb + (size_t)(n0 + nf * 16 + lr) * (9 * CI) + tap * CI + ci0);
        #pragma unroll
        for (int mf = 0; mf < 4; ++mf) {
          int px = mf * 16 + lr + dx;
          bf16x8 afr = {0, 0, 0, 0, 0, 0, 0, 0};
          if ((unsigned)px < 64u)
            afr = *reinterpret_cast<const bf16x8*>(arow + (size_t)px * CI + ci0);
          #pragma unroll
          for (int nf = 0; nf < 2; ++nf)
            acc[mf][nf] = __builtin_amdgcn_mfma_f32_16x16x32_bf16(
                afr, bfr[nf], acc[mf][nf], 0, 0, 0);
        }
      }
    }
  }

  #pragma unroll
  for (int nf = 0; nf < 2; ++nf) {
    int n = n0 + nf * 16 + lr;
    float aS = bg[n] * rsqrtf(bv[n] + 1e-5f);
    float aB = (bc[n] - bm[n]) * aS + bb[n];
    #pragma unroll
    for (int mf = 0; mf < 4; ++mf)
      #pragma unroll
      for (int i = 0; i < 4; ++i) {
        int m = mf * 16 + (lane >> 4) * 4 + i;
        float v = fmaxf(acc[mf][nf][i] * aS + aB, 0.f);
        Y[((size_t)(b * 4096 + y * 64 + m)) * 128 + n] = f2bf(v);
      }
  }
}

// ---------------- bf16 MFMA GEMM: C[M,N] = A[M,K] @ W[N,K]^T ----------------
// Block: 4 waves, tile M=64 x N=128 (wave N=32). EPI 0: split xm/z fp32.
// EPI 1: plain fp32 C0 [M][128].
template<int KDIM, int EPI>
__global__ __launch_bounds__(256) void gemm_mfma(
    const unsigned short* __restrict__ A,   // [M][KDIM] bf16
    const unsigned short* __restrict__ Wn,  // [N][KDIM] bf16
    float* __restrict__ C0, float* __restrict__ C1)
{
  const int lane = threadIdx.x & 63;
  const int wid  = threadIdx.x >> 6;
  const int m0 = blockIdx.x * 64;
  const int n0 = blockIdx.y * 128 + wid * 32;
  const int lr = lane & 15, lk = (lane >> 4) * 8;

  f32x4 acc[4][2];
  #pragma unroll
  for (int i = 0; i < 4; ++i)
    #pragma unroll
    for (int j = 0; j < 2; ++j) acc[i][j] = f32x4{0.f, 0.f, 0.f, 0.f};

  const unsigned short* Ab = A + (size_t)m0 * KDIM;
  #pragma unroll 4
  for (int k0 = 0; k0 < KDIM; k0 += 32) {
    const int kc = k0 + lk;
    bf16x8 bfr[2];
    #pragma unroll
    for (int nf = 0; nf < 2; ++nf)
      bfr[nf] = *reinterpret_cast<const bf16x8*>(
          Wn + (size_t)(n0 + nf * 16 + lr) * KDIM + kc);
    #pragma unroll
    for (int mf = 0; mf < 4; ++mf) {
      bf16x8 afr = *reinterpret_cast<const bf16x8*>(
          Ab + (size_t)(mf * 16 + lr) * KDIM + kc);
      #pragma unroll
      for (int nf = 0; nf < 2; ++nf)
        acc[mf][nf] = __builtin_amdgcn_mfma_f32_16x16x32_bf16(
            afr, bfr[nf], acc[mf][nf], 0, 0, 0);
    }
  }

  #pragma unroll
  for (int nf = 0; nf < 2; ++nf) {
    int n = n0 + nf * 16 + lr;
    #pragma unroll
    for (int mf = 0; mf < 4; ++mf)
      #pragma unroll
      for (int i = 0; i < 4; ++i) {
        int m = m0 + mf * 16 + (lane >> 4) * 4 + i;
        float v = acc[mf][nf][i];
        if (EPI == 0) {
          if (n < 256) C0[(size_t)m * 256 + n] = v;
          else         C1[(size_t)m * 256 + (n - 256)] = v;
        } else {
          C0[(size_t)m * 128 + n] = v;
        }
      }
  }
}

// ---------------- fp32 GEMM (kept for x_proj, N=40) -------------------------
__global__ __launch_bounds__(256) void gemm_nt(
    const float* __restrict__ A, const float* __restrict__ W,
    float* __restrict__ C, int M, int N, int K)
{
  __shared__ float As[16][68];
  __shared__ float Bs[16][68];
  const int m0 = blockIdx.x * 64, n0 = blockIdx.y * 64;
  const int tid = threadIdx.x;
  const int tx = tid & 15, ty = tid >> 4;
  const int lr = tid >> 2;
  const int lk = (tid & 3) * 4;
  float acc[4][4] = {};

  for (int k0 = 0; k0 < K; k0 += 16) {
    float4 av = *reinterpret_cast<const float4*>(&A[(size_t)(m0 + lr) * K + k0 + lk]);
    float4 wv = make_float4(0.f, 0.f, 0.f, 0.f);
    if (n0 + lr < N)
      wv = *reinterpret_cast<const float4*>(&W[(size_t)(n0 + lr) * K + k0 + lk]);
    As[lk + 0][lr] = av.x; As[lk + 1][lr] = av.y;
    As[lk + 2][lr] = av.z; As[lk + 3][lr] = av.w;
    Bs[lk + 0][lr] = wv.x; Bs[lk + 1][lr] = wv.y;
    Bs[lk + 2][lr] = wv.z; Bs[lk + 3][lr] = wv.w;
    __syncthreads();
    #pragma unroll
    for (int k = 0; k < 16; ++k) {
      float4 a4 = *reinterpret_cast<const float4*>(&As[k][ty * 4]);
      float4 b4 = *reinterpret_cast<const float4*>(&Bs[k][tx * 4]);
      float avv[4] = {a4.x, a4.y, a4.z, a4.w};
      float bvv[4] = {b4.x, b4.y, b4.z, b4.w};
      #pragma unroll
      for (int i = 0; i < 4; ++i)
        #pragma unroll
        for (int j = 0; j < 4; ++j)
          acc[i][j] = fmaf(avv[i], bvv[j], acc[i][j]);
    }
    __syncthreads();
  }
  #pragma unroll
  for (int i = 0; i < 4; ++i) {
    int m = m0 + ty * 4 + i;
    #pragma unroll
    for (int j = 0; j < 4; ++j) {
      int n = n0 + tx * 4 + j;
      if (n < N) C[(size_t)m * N + n] = acc[i][j];
    }
  }
}

// ---------------- depthwise causal conv1d (DCONV=4) + silu, float4 ----------
__global__ __launch_bounds__(256) void conv1d_silu(
    const float* __restrict__ xm,   // (T,256)
    const float* __restrict__ w,    // (256,4)
    const float* __restrict__ bias, // (256)
    float* __restrict__ out)        // (T,256)
{
  __shared__ float ws4[4][256];
  __shared__ float bsh[256];
  for (int i = threadIdx.x; i < 1024; i += 256)
    ws4[i >> 8][i & 255] = w[(i & 255) * 4 + (i >> 8)];
  bsh[threadIdx.x] = bias[threadIdx.x];
  __syncthreads();
  const int total = 8 * 4096 * 64;
  for (int idx = blockIdx.x * 256 + threadIdx.x; idx < total;
       idx += gridDim.x * 256) {
    int d4 = idx & 63, t = idx >> 6, l = t & 4095;
    int d = d4 * 4;
    float4 acc = *reinterpret_cast<const float4*>(&bsh[d]);
    #pragma unroll
    for (int j = 0; j < 4; ++j) {
      if (l - 3 + j >= 0) {
        float4 xv = *reinterpret_cast<const float4*>(&xm[(size_t)(t - 3 + j) * 256 + d]);
        float4 wv = *reinterpret_cast<const float4*>(&ws4[j][d]);
        acc.x = fmaf(xv.x, wv.x, acc.x);
        acc.y = fmaf(xv.y, wv.y, acc.y);
        acc.z = fmaf(xv.z, wv.z, acc.z);
        acc.w = fmaf(xv.w, wv.w, acc.w);
      }
    }
    acc.x = siluf(acc.x); acc.y = siluf(acc.y);
    acc.z = siluf(acc.z); acc.w = siluf(acc.w);
    *reinterpret_cast<float4*>(&out[(size_t)t * 256 + d]) = acc;
  }
}

// ---------------- chunked selective scan ------------------------------------
__global__ __launch_bounds__(256) void scan_pass1(
    const float* __restrict__ xssm, const float* __restrict__ xdb,
    const float* __restrict__ dtw, const float* __restrict__ dtb,
    const float* __restrict__ A_log,
    float* __restrict__ Q, float* __restrict__ S)
{
  __shared__ float sh[CL][40];
  const int c = blockIdx.x, b = blockIdx.y;
  const int d = threadIdx.x;
  const int l0 = c * CL;
  const float* src = &xdb[((size_t)b * 4096 + l0) * 40];
  for (int i = threadIdx.x; i < CL * 40; i += 256)
    sh[i / 40][i % 40] = src[i];

  float wdt[8];
  #pragma unroll
  for (int r = 0; r < 8; ++r) wdt[r] = dtw[d * 8 + r];
  const float bdt = dtb[d];
  float Aneg[16], h[16];
  #pragma unroll
  for (int s = 0; s < 16; ++s) {
    Aneg[s] = -__expf(A_log[d * 16 + s]);
    h[s] = 0.f;
  }
  __syncthreads();

  float sdt = 0.f;
  const size_t xbase = ((size_t)b * 4096 + l0) * 256 + d;
  float xv = xssm[xbase];
  for (int l = 0; l < CL; ++l) {
    float xn = (l + 1 < CL) ? xssm[xbase + (size_t)(l + 1) * 256] : 0.f;
    float acc = bdt;
    #pragma unroll
    for (int r = 0; r < 8; ++r) acc = fmaf(sh[l][r], wdt[r], acc);
    float dt = (acc > 20.f) ? acc : log1pf(__expf(acc));
    sdt += dt;
    float dtx = dt * xv;
    #pragma unroll
    for (int s = 0; s < 16; ++s) {
      float dA = __expf(dt * Aneg[s]);
      h[s] = fmaf(dA, h[s], dtx * sh[l][8 + s]);
    }
    xv = xn;
  }
  float* q = &Q[(((size_t)b * NC + c) * 256 + d) * 16];
  #pragma unroll
  for (int s = 0; s < 16; ++s) q[s] = h[s];
  S[((size_t)b * NC + c) * 256 + d] = sdt;
}

__global__ __launch_bounds__(256) void scan_combine(
    float* __restrict__ Q, const float* __restrict__ S,
    const float* __restrict__ A_log)
{
  int g = blockIdx.x * 256 + threadIdx.x;
  int b = g >> 12, d = (g >> 4) & 255, s = g & 15;
  float Aneg = -__expf(A_log[d * 16 + s]);
  float h = 0.f;
  for (int c = 0; c < NC; ++c) {
    size_t qi = (((size_t)b * NC + c) * 256 + d) * 16 + s;
    float q  = Q[qi];
    float sd = S[((size_t)b * NC + c) * 256 + d];
    Q[qi] = h;
    h = fmaf(__expf(Aneg * sd), h, q);
  }
}

// Pass 3: re-scan from h_start; y = C.h + D*x, silu(z) gate, write y bf16.
__global__ __launch_bounds__(256) void scan_pass2(
    const float* __restrict__ xssm, const float* __restrict__ xdb,
    const float* __restrict__ zb,
    const float* __restrict__ dtw, const float* __restrict__ dtb,
    const float* __restrict__ A_log, const float* __restrict__ Dp,
    const float* __restrict__ Hstart, unsigned short* __restrict__ ybf)
{
  __shared__ float sh[CL][40];
  const int c = blockIdx.x, b = blockIdx.y;
  const int d = threadIdx.x;
  const int l0 = c * CL;
  const float* src = &xdb[((size_t)b * 4096 + l0) * 40];
  for (int i = threadIdx.x; i < CL * 40; i += 256)
    sh[i / 40][i % 40] = src[i];

  float wdt[8];
  #pragma unroll
  for (int r = 0; r < 8; ++r) wdt[r] = dtw[d * 8 + r];
  const float bdt = dtb[d];
  const float Dd = Dp[d];
  float Aneg[16], h[16];
  const float* hs = &Hstart[(((size_t)b * NC + c) * 256 + d) * 16];
  #pragma unroll
  for (int s = 0; s < 16; ++s) {
    Aneg[s] = -__expf(A_log[d * 16 + s]);
    h[s] = hs[s];
  }
  __syncthreads();

  const size_t xbase = ((size_t)b * 4096 + l0) * 256 + d;
  float xv = xssm[xbase], zv = zb[xbase];
  for (int l = 0; l < CL; ++l) {
    float xn = 0.f, zn = 0.f;
    if (l + 1 < CL) {
      xn = xssm[xbase + (size_t)(l + 1) * 256];
      zn = zb[xbase + (size_t)(l + 1) * 256];
    }
    float acc = bdt;
    #pragma unroll
    for (int r = 0; r < 8; ++r) acc = fmaf(sh[l][r], wdt[r], acc);
    float dt = (acc > 20.f) ? acc : log1pf(__expf(acc));
    float dtx = dt * xv;
    float y = 0.f;
    #pragma unroll
    for (int s = 0; s < 16; ++s) {
      float dA = __expf(dt * Aneg[s]);
      h[s] = fmaf(dA, h[s], dtx * sh[l][8 + s]);
      y = fmaf(h[s], sh[l][24 + s], y);
    }
    y = (y + Dd * xv) * siluf(zv);
    ybf[xbase + (size_t)l * 256] = f2bf(y);
    xv = xn; zv = zn;
  }
}

// ---------------- LayerNorm(128) + transpose to NCHW ------------------------
__global__ __launch_bounds__(256) void ln_transpose(
    const float* __restrict__ X,
    const float* __restrict__ g, const float* __restrict__ b,
    float* __restrict__ out)
{
  __shared__ float buf[64][129];
  const int t0 = blockIdx.x * 64;
  const int bb = t0 >> 12, l0 = t0 & 4095;
  const int tid = threadIdx.x;
  for (int idx = tid; idx < 64 * 128; idx += 256)
    buf[idx >> 7][idx & 127] = X[(size_t)t0 * 128 + idx];
  __syncthreads();
  const int tt = tid >> 2, q = tid & 3;
  float s = 0.f, sq = 0.f;
  #pragma unroll
  for (int i = 0; i < 32; ++i) {
    float v = buf[tt][q * 32 + i];
    s += v; sq += v * v;
  }
  s  += __shfl_xor(s, 1);  s  += __shfl_xor(s, 2);
  sq += __shfl_xor(sq, 1); sq += __shfl_xor(sq, 2);
  float mu = s * (1.f / 128.f);
  float var = sq * (1.f / 128.f) - mu * mu;
  float rstd = rsqrtf(fmaxf(var, 0.f) + 1e-5f);
  #pragma unroll
  for (int i = 0; i < 32; ++i) {
    int c = q * 32 + i;
    buf[tt][c] = (buf[tt][c] - mu) * rstd * g[c] + b[c];
  }
  __syncthreads();
  for (int idx = tid; idx < 64 * 128; idx += 256) {
    int c = idx >> 6, t2 = idx & 63;
    out[((size_t)bb * 128 + c) * 4096 + l0 + t2] = buf[t2][c];
  }
}

// ---------------------------------------------------------------------------
extern "C" void kernel_launch(void* const* d_in, const int* in_sizes, int n_in,
                              void* d_out, int out_size, void* d_ws, size_t ws_size,
                              hipStream_t stream) {
  const float* x        = (const float*)d_in[0];
  const float* conv1_w  = (const float*)d_in[1];
  const float* conv1_b  = (const float*)d_in[2];
  const float* bn1_g    = (const float*)d_in[3];
  const float* bn1_b    = (const float*)d_in[4];
  const float* bn1_m    = (const float*)d_in[5];
  const float* bn1_v    = (const float*)d_in[6];
  const float* conv2_w  = (const float*)d_in[7];
  const float* conv2_b  = (const float*)d_in[8];
  const float* bn2_g    = (const float*)d_in[9];
  const float* bn2_b    = (const float*)d_in[10];
  const float* bn2_m    = (const float*)d_in[11];
  const float* bn2_v    = (const float*)d_in[12];
  const float* in_proj_w  = (const float*)d_in[13];  // (512,128)
  const float* conv1d_w   = (const float*)d_in[14];  // (256,1,4)
  const float* conv1d_b   = (const float*)d_in[15];
  const float* x_proj_w   = (const float*)d_in[16];  // (40,256)
  const float* dt_proj_w  = (const float*)d_in[17];  // (256,8)
  const float* dt_proj_b  = (const float*)d_in[18];
  const float* A_log      = (const float*)d_in[19];  // (256,16)
  const float* Dp         = (const float*)d_in[20];  // (256)
  const float* out_proj_w = (const float*)d_in[21];  // (128,256)
  const float* ln_g       = (const float*)d_in[22];
  const float* ln_b       = (const float*)d_in[23];
  float* out = (float*)d_out;

  float* ws_f = (float*)d_ws;
  // workspace (float units), lifetime-reuse; peak 30,830,592 f = 123 MB
  unsigned short* xb   = (unsigned short*)ws_f;           // bf16, dead pre-xm
  float*          xm   = ws_f;                            // [0, 8388608)
  unsigned short* ybf  = (unsigned short*)ws_f;           // [0, 4194304) after xm dead
  float*          outs = ws_f + 4194304;                  // [4194304, 8388608)
  float*          zb   = ws_f + 8388608;                  // [8388608, 16777216)
  float*          xssm = ws_f + 16777216;                 // [16777216, 25165824)
  unsigned short* h1   = (unsigned short*)(ws_f + 25165824);  // dead pre-Q
  float*          Qbuf = ws_f + 25165824;                 // [25165824, 27262976)
  unsigned short* seqb = (unsigned short*)(ws_f + 27262976);  // dead pre-S
  float*          Sbuf = ws_f + 27262976;                 // 131072 f
  float*          xdb  = ws_f + 29360128;                 // 1310720 f
  unsigned short* wb1  = (unsigned short*)(ws_f + 30670848);  // 73728 bf16
  unsigned short* wb2  = (unsigned short*)(ws_f + 30707712);  // 147456 bf16
  unsigned short* win  = (unsigned short*)(ws_f + 30781440);  // 65536 bf16
  unsigned short* wout = (unsigned short*)(ws_f + 30814208);  // 32768 bf16

  // pre-passes
  nchw2nhwc_bf16<<<512, 256, 0, stream>>>(x, xb);
  convw_prep<64><<<(73728 + 255) / 256, 256, 0, stream>>>(conv1_w, wb1);
  convw_prep<128><<<(147456 + 255) / 256, 256, 0, stream>>>(conv2_w, wb2);
  f32_to_bf16<<<256, 256, 0, stream>>>(in_proj_w, win, 65536);
  f32_to_bf16<<<128, 256, 0, stream>>>(out_proj_w, wout, 32768);

  // convs (MFMA, BN+ReLU fused, bf16 NHWC out)
  conv_mfma<64><<<dim3(64, 8), 256, 0, stream>>>(
      xb, wb1, conv1_b, bn1_g, bn1_b, bn1_m, bn1_v, h1);
  conv_mfma<128><<<dim3(64, 8), 256, 0, stream>>>(
      h1, wb2, conv2_b, bn2_g, bn2_b, bn2_m, bn2_v, seqb);

  // in_proj (one GEMM, N=512 -> xm | z)
  gemm_mfma<128, 0><<<dim3(512, 4), 256, 0, stream>>>(seqb, win, xm, zb);

  conv1d_silu<<<2048, 256, 0, stream>>>(xm, conv1d_w, conv1d_b, xssm);
  gemm_nt<<<dim3(512, 1), 256, 0, stream>>>(xssm, x_proj_w, xdb, 32768, 40, 256);

  scan_pass1<<<dim3(NC, 8), 256, 0, stream>>>(
      xssm, xdb, dt_proj_w, dt_proj_b, A_log, Qbuf, Sbuf);
  scan_combine<<<128, 256, 0, stream>>>(Qbuf, Sbuf, A_log);
  scan_pass2<<<dim3(NC, 8), 256, 0, stream>>>(
      xssm, xdb, zb, dt_proj_w, dt_proj_b, A_log, Dp, Qbuf, ybf);

  // out_proj (MFMA) + LN/transpose
  gemm_mfma<256, 1><<<dim3(512, 1), 256, 0, stream>>>(ybf, wout, outs, nullptr);
  ln_transpose<<<512, 256, 0, stream>>>(outs, ln_g, ln_b, out);
}

// Round 4
// 277.203 us; speedup vs baseline: 6.9828x; 1.1448x over previous
//
#include <hip/hip_runtime.h>
#include <hip/hip_bf16.h>

// ---------------------------------------------------------------------------
// MambaConvBlock fused pipeline. Round 4: scan rework (NC=128, float4 LDS,
// cheap transcendentals). Sizes: B=8, CIN=64, COUT=128, H=W=64, L=4096,
// T=32768, DINNER=256, DSTATE=16, DTRANK=8, DCONV=4.
// ---------------------------------------------------------------------------

typedef __attribute__((ext_vector_type(8))) short bf16x8;
typedef __attribute__((ext_vector_type(4))) float f32x4;

#define DEV __device__ __forceinline__

DEV float siluf(float v) {
  return v * __builtin_amdgcn_rcpf(1.f + __expf(-v));
}

DEV unsigned short f2bf(float f) {
  __hip_bfloat16 h = __float2bfloat16(f);
  return *reinterpret_cast<unsigned short*>(&h);
}

constexpr int NC = 128;  // chunks per batch
constexpr int CL = 32;   // chunk length (NC*CL = 4096)

// ---------------- pre-pass: NCHW fp32 -> NHWC bf16 --------------------------
__global__ __launch_bounds__(256) void nchw2nhwc_bf16(
    const float* __restrict__ X, unsigned short* __restrict__ Xb)
{
  __shared__ float t[64][65];
  const int by = blockIdx.x;            // b*64 + y
  const int b = by >> 6, y = by & 63;
  const int tid = threadIdx.x;
  for (int i = tid; i < 4096; i += 256) {
    int c = i >> 6, xx = i & 63;
    t[c][xx] = X[(((size_t)b * 64 + c) * 64 + y) * 64 + xx];
  }
  __syncthreads();
  for (int i = tid; i < 4096; i += 256) {
    int xx = i >> 6, c = i & 63;
    Xb[(((size_t)b * 64 + y) * 64 + xx) * 64 + c] = f2bf(t[c][xx]);
  }
}

// ---------------- pre-pass: conv weights -> bf16 [co][tap][ci] --------------
template<int CI>
__global__ void convw_prep(const float* __restrict__ W,
                           unsigned short* __restrict__ Wb)
{
  int idx = blockIdx.x * 256 + threadIdx.x;
  if (idx >= 128 * 9 * CI) return;
  int co = idx / (9 * CI), r = idx % (9 * CI);
  int t = r / CI, ci = r % CI;
  Wb[idx] = f2bf(W[((size_t)co * CI + ci) * 9 + t]);
}

__global__ void f32_to_bf16(const float* __restrict__ A,
                            unsigned short* __restrict__ B, int n)
{
  int i = blockIdx.x * 256 + threadIdx.x;
  if (i < n) B[i] = f2bf(A[i]);
}

// ---------------- conv3x3 + BN + ReLU as implicit-GEMM MFMA -----------------
template<int CI>
__global__ __launch_bounds__(256) void conv_mfma(
    const unsigned short* __restrict__ Xb,   // [b][64][64][CI] bf16
    const unsigned short* __restrict__ Wb,   // [128][9][CI]    bf16
    const float* __restrict__ bc,
    const float* __restrict__ bg, const float* __restrict__ bb,
    const float* __restrict__ bm, const float* __restrict__ bv,
    unsigned short* __restrict__ Y)          // [b][y][x][128]  bf16
{
  const int lane = threadIdx.x & 63;
  const int wid  = threadIdx.x >> 6;
  const int n0 = wid * 32;
  const int y = blockIdx.x, b = blockIdx.y;
  const int lr = lane & 15, lk = (lane >> 4) * 8;

  f32x4 acc[4][2];
  #pragma unroll
  for (int i = 0; i < 4; ++i)
    #pragma unroll
    for (int j = 0; j < 2; ++j) acc[i][j] = f32x4{0.f, 0.f, 0.f, 0.f};

  #pragma unroll
  for (int dy = -1; dy <= 1; ++dy) {
    int yy = y + dy;
    if (yy < 0 || yy >= 64) continue;
    const unsigned short* arow = Xb + ((size_t)(b * 64 + yy) * 64) * CI;
    #pragma unroll
    for (int dx = -1; dx <= 1; ++dx) {
      const int tap = (dy + 1) * 3 + (dx + 1);
      #pragma unroll
      for (int kk = 0; kk < CI / 32; ++kk) {
        const int ci0 = kk * 32 + lk;
        bf16x8 bfr[2];
        #pragma unroll
        for (int nf = 0; nf < 2; ++nf)
          bfr[nf] = *reinterpret_cast<const bf16x8*>(
              Wb + (size_t)(n0 + nf * 16 + lr) * (9 * CI) + tap * CI + ci0);
        #pragma unroll
        for (int mf = 0; mf < 4; ++mf) {
          int px = mf * 16 + lr + dx;
          bf16x8 afr = {0, 0, 0, 0, 0, 0, 0, 0};
          if ((unsigned)px < 64u)
            afr = *reinterpret_cast<const bf16x8*>(arow + (size_t)px * CI + ci0);
          #pragma unroll
          for (int nf = 0; nf < 2; ++nf)
            acc[mf][nf] = __builtin_amdgcn_mfma_f32_16x16x32_bf16(
                afr, bfr[nf], acc[mf][nf], 0, 0, 0);
        }
      }
    }
  }

  #pragma unroll
  for (int nf = 0; nf < 2; ++nf) {
    int n = n0 + nf * 16 + lr;
    float aS = bg[n] * rsqrtf(bv[n] + 1e-5f);
    float aB = (bc[n] - bm[n]) * aS + bb[n];
    #pragma unroll
    for (int mf = 0; mf < 4; ++mf)
      #pragma unroll
      for (int i = 0; i < 4; ++i) {
        int m = mf * 16 + (lane >> 4) * 4 + i;
        float v = fmaxf(acc[mf][nf][i] * aS + aB, 0.f);
        Y[((size_t)(b * 4096 + y * 64 + m)) * 128 + n] = f2bf(v);
      }
  }
}

// ---------------- bf16 MFMA GEMM: C[M,N] = A[M,K] @ W[N,K]^T ----------------
template<int KDIM, int EPI>
__global__ __launch_bounds__(256) void gemm_mfma(
    const unsigned short* __restrict__ A,   // [M][KDIM] bf16
    const unsigned short* __restrict__ Wn,  // [N][KDIM] bf16
    float* __restrict__ C0, float* __restrict__ C1)
{
  const int lane = threadIdx.x & 63;
  const int wid  = threadIdx.x >> 6;
  const int m0 = blockIdx.x * 64;
  const int n0 = blockIdx.y * 128 + wid * 32;
  const int lr = lane & 15, lk = (lane >> 4) * 8;

  f32x4 acc[4][2];
  #pragma unroll
  for (int i = 0; i < 4; ++i)
    #pragma unroll
    for (int j = 0; j < 2; ++j) acc[i][j] = f32x4{0.f, 0.f, 0.f, 0.f};

  const unsigned short* Ab = A + (size_t)m0 * KDIM;
  #pragma unroll 4
  for (int k0 = 0; k0 < KDIM; k0 += 32) {
    const int kc = k0 + lk;
    bf16x8 bfr[2];
    #pragma unroll
    for (int nf = 0; nf < 2; ++nf)
      bfr[nf] = *reinterpret_cast<const bf16x8*>(
          Wn + (size_t)(n0 + nf * 16 + lr) * KDIM + kc);
    #pragma unroll
    for (int mf = 0; mf < 4; ++mf) {
      bf16x8 afr = *reinterpret_cast<const bf16x8*>(
          Ab + (size_t)(mf * 16 + lr) * KDIM + kc);
      #pragma unroll
      for (int nf = 0; nf < 2; ++nf)
        acc[mf][nf] = __builtin_amdgcn_mfma_f32_16x16x32_bf16(
            afr, bfr[nf], acc[mf][nf], 0, 0, 0);
    }
  }

  #pragma unroll
  for (int nf = 0; nf < 2; ++nf) {
    int n = n0 + nf * 16 + lr;
    #pragma unroll
    for (int mf = 0; mf < 4; ++mf)
      #pragma unroll
      for (int i = 0; i < 4; ++i) {
        int m = m0 + mf * 16 + (lane >> 4) * 4 + i;
        float v = acc[mf][nf][i];
        if (EPI == 0) {
          if (n < 256) C0[(size_t)m * 256 + n] = v;
          else         C1[(size_t)m * 256 + (n - 256)] = v;
        } else {
          C0[(size_t)m * 128 + n] = v;
        }
      }
  }
}

// ---------------- fp32 GEMM (x_proj, N=40) ----------------------------------
__global__ __launch_bounds__(256) void gemm_nt(
    const float* __restrict__ A, const float* __restrict__ W,
    float* __restrict__ C, int M, int N, int K)
{
  __shared__ float As[16][68];
  __shared__ float Bs[16][68];
  const int m0 = blockIdx.x * 64, n0 = blockIdx.y * 64;
  const int tid = threadIdx.x;
  const int tx = tid & 15, ty = tid >> 4;
  const int lr = tid >> 2;
  const int lk = (tid & 3) * 4;
  float acc[4][4] = {};

  for (int k0 = 0; k0 < K; k0 += 16) {
    float4 av = *reinterpret_cast<const float4*>(&A[(size_t)(m0 + lr) * K + k0 + lk]);
    float4 wv = make_float4(0.f, 0.f, 0.f, 0.f);
    if (n0 + lr < N)
      wv = *reinterpret_cast<const float4*>(&W[(size_t)(n0 + lr) * K + k0 + lk]);
    As[lk + 0][lr] = av.x; As[lk + 1][lr] = av.y;
    As[lk + 2][lr] = av.z; As[lk + 3][lr] = av.w;
    Bs[lk + 0][lr] = wv.x; Bs[lk + 1][lr] = wv.y;
    Bs[lk + 2][lr] = wv.z; Bs[lk + 3][lr] = wv.w;
    __syncthreads();
    #pragma unroll
    for (int k = 0; k < 16; ++k) {
      float4 a4 = *reinterpret_cast<const float4*>(&As[k][ty * 4]);
      float4 b4 = *reinterpret_cast<const float4*>(&Bs[k][tx * 4]);
      float avv[4] = {a4.x, a4.y, a4.z, a4.w};
      float bvv[4] = {b4.x, b4.y, b4.z, b4.w};
      #pragma unroll
      for (int i = 0; i < 4; ++i)
        #pragma unroll
        for (int j = 0; j < 4; ++j)
          acc[i][j] = fmaf(avv[i], bvv[j], acc[i][j]);
    }
    __syncthreads();
  }
  #pragma unroll
  for (int i = 0; i < 4; ++i) {
    int m = m0 + ty * 4 + i;
    #pragma unroll
    for (int j = 0; j < 4; ++j) {
      int n = n0 + tx * 4 + j;
      if (n < N) C[(size_t)m * N + n] = acc[i][j];
    }
  }
}

// ---------------- depthwise causal conv1d (DCONV=4) + silu, float4 ----------
__global__ __launch_bounds__(256) void conv1d_silu(
    const float* __restrict__ xm,   // (T,256)
    const float* __restrict__ w,    // (256,4)
    const float* __restrict__ bias, // (256)
    float* __restrict__ out)        // (T,256)
{
  __shared__ float ws4[4][256];
  __shared__ float bsh[256];
  for (int i = threadIdx.x; i < 1024; i += 256)
    ws4[i >> 8][i & 255] = w[(i & 255) * 4 + (i >> 8)];
  bsh[threadIdx.x] = bias[threadIdx.x];
  __syncthreads();
  const int total = 8 * 4096 * 64;
  for (int idx = blockIdx.x * 256 + threadIdx.x; idx < total;
       idx += gridDim.x * 256) {
    int d4 = idx & 63, t = idx >> 6, l = t & 4095;
    int d = d4 * 4;
    float4 acc = *reinterpret_cast<const float4*>(&bsh[d]);
    #pragma unroll
    for (int j = 0; j < 4; ++j) {
      if (l - 3 + j >= 0) {
        float4 xv = *reinterpret_cast<const float4*>(&xm[(size_t)(t - 3 + j) * 256 + d]);
        float4 wv = *reinterpret_cast<const float4*>(&ws4[j][d]);
        acc.x = fmaf(xv.x, wv.x, acc.x);
        acc.y = fmaf(xv.y, wv.y, acc.y);
        acc.z = fmaf(xv.z, wv.z, acc.z);
        acc.w = fmaf(xv.w, wv.w, acc.w);
      }
    }
    acc.x = siluf(acc.x); acc.y = siluf(acc.y);
    acc.z = siluf(acc.z); acc.w = siluf(acc.w);
    *reinterpret_cast<float4*>(&out[(size_t)t * 256 + d]) = acc;
  }
}

// ---------------- chunked selective scan ------------------------------------
// Pass 1: per (b,chunk), thread d holds h[16]; emits Q (chunk-end state from
// zero init) and S = sum(dt). dt_proj+softplus fused; xdb rows staged in LDS,
// read back as float4 broadcasts.
__global__ __launch_bounds__(256) void scan_pass1(
    const float* __restrict__ xssm, const float* __restrict__ xdb,
    const float* __restrict__ dtw, const float* __restrict__ dtb,
    const float* __restrict__ A_log,
    float* __restrict__ Q, float* __restrict__ S)
{
  __shared__ __align__(16) float sh[CL][40];
  const int c = blockIdx.x, b = blockIdx.y;
  const int d = threadIdx.x;
  {
    const float4* src = reinterpret_cast<const float4*>(
        &xdb[((size_t)b * 4096 + c * CL) * 40]);
    float4* dst = reinterpret_cast<float4*>(&sh[0][0]);
    for (int i = threadIdx.x; i < CL * 10; i += 256) dst[i] = src[i];
  }
  float4 w0 = *reinterpret_cast<const float4*>(&dtw[d * 8]);
  float4 w1 = *reinterpret_cast<const float4*>(&dtw[d * 8 + 4]);
  const float bdt = dtb[d];
  float Aneg[16], h[16];
  #pragma unroll
  for (int s = 0; s < 16; ++s) {
    Aneg[s] = -__expf(A_log[d * 16 + s]);
    h[s] = 0.f;
  }
  __syncthreads();

  float sdt = 0.f;
  const size_t xbase = ((size_t)b * 4096 + (size_t)c * CL) * 256 + d;
  for (int l = 0; l < CL; ++l) {
    const float4* row = reinterpret_cast<const float4*>(sh[l]);
    float4 r0 = row[0], r1 = row[1];
    float acc = bdt;
    acc = fmaf(r0.x, w0.x, acc); acc = fmaf(r0.y, w0.y, acc);
    acc = fmaf(r0.z, w0.z, acc); acc = fmaf(r0.w, w0.w, acc);
    acc = fmaf(r1.x, w1.x, acc); acc = fmaf(r1.y, w1.y, acc);
    acc = fmaf(r1.z, w1.z, acc); acc = fmaf(r1.w, w1.w, acc);
    float dt = (acc > 20.f) ? acc : __logf(1.f + __expf(acc));
    sdt += dt;
    float xv = xssm[xbase + (size_t)l * 256];
    float dtx = dt * xv;
    #pragma unroll
    for (int q = 0; q < 4; ++q) {
      float4 Bq = row[2 + q];
      float bb4[4] = {Bq.x, Bq.y, Bq.z, Bq.w};
      #pragma unroll
      for (int j = 0; j < 4; ++j) {
        int s = q * 4 + j;
        float dA = __expf(dt * Aneg[s]);
        h[s] = fmaf(dA, h[s], dtx * bb4[j]);
      }
    }
  }
  float4* q4 = reinterpret_cast<float4*>(
      &Q[(((size_t)b * NC + c) * 256 + d) * 16]);
  #pragma unroll
  for (int q = 0; q < 4; ++q)
    q4[q] = make_float4(h[q * 4], h[q * 4 + 1], h[q * 4 + 2], h[q * 4 + 3]);
  S[((size_t)b * NC + c) * 256 + d] = sdt;
}

// Pass 2 (combine): h_start[c] = P(c-1)*h_start[c-1] + Q[c-1]; in place.
__global__ __launch_bounds__(256) void scan_combine(
    float* __restrict__ Q, const float* __restrict__ S,
    const float* __restrict__ A_log)
{
  int g = blockIdx.x * 256 + threadIdx.x;   // 32768 total
  int b = g >> 12, d = (g >> 4) & 255, s = g & 15;
  float Aneg = -__expf(A_log[d * 16 + s]);
  float h = 0.f;
  for (int c = 0; c < NC; ++c) {
    size_t qi = (((size_t)b * NC + c) * 256 + d) * 16 + s;
    float q  = Q[qi];
    float sd = S[((size_t)b * NC + c) * 256 + d];
    Q[qi] = h;
    h = fmaf(__expf(Aneg * sd), h, q);
  }
}

// Pass 3: re-scan from h_start; y = C.h + D*x, silu(z) gate, write y bf16.
__global__ __launch_bounds__(256) void scan_pass2(
    const float* __restrict__ xssm, const float* __restrict__ xdb,
    const float* __restrict__ zb,
    const float* __restrict__ dtw, const float* __restrict__ dtb,
    const float* __restrict__ A_log, const float* __restrict__ Dp,
    const float* __restrict__ Hstart, unsigned short* __restrict__ ybf)
{
  __shared__ __align__(16) float sh[CL][40];
  const int c = blockIdx.x, b = blockIdx.y;
  const int d = threadIdx.x;
  {
    const float4* src = reinterpret_cast<const float4*>(
        &xdb[((size_t)b * 4096 + c * CL) * 40]);
    float4* dst = reinterpret_cast<float4*>(&sh[0][0]);
    for (int i = threadIdx.x; i < CL * 10; i += 256) dst[i] = src[i];
  }
  float4 w0 = *reinterpret_cast<const float4*>(&dtw[d * 8]);
  float4 w1 = *reinterpret_cast<const float4*>(&dtw[d * 8 + 4]);
  const float bdt = dtb[d];
  const float Dd = Dp[d];
  float Aneg[16], h[16];
  const float4* hs4 = reinterpret_cast<const float4*>(
      &Hstart[(((size_t)b * NC + c) * 256 + d) * 16]);
  #pragma unroll
  for (int q = 0; q < 4; ++q) {
    float4 hv = hs4[q];
    h[q * 4 + 0] = hv.x; h[q * 4 + 1] = hv.y;
    h[q * 4 + 2] = hv.z; h[q * 4 + 3] = hv.w;
  }
  #pragma unroll
  for (int s = 0; s < 16; ++s) Aneg[s] = -__expf(A_log[d * 16 + s]);
  __syncthreads();

  const size_t xbase = ((size_t)b * 4096 + (size_t)c * CL) * 256 + d;
  for (int l = 0; l < CL; ++l) {
    const float4* row = reinterpret_cast<const float4*>(sh[l]);
    float4 r0 = row[0], r1 = row[1];
    float acc = bdt;
    acc = fmaf(r0.x, w0.x, acc); acc = fmaf(r0.y, w0.y, acc);
    acc = fmaf(r0.z, w0.z, acc); acc = fmaf(r0.w, w0.w, acc);
    acc = fmaf(r1.x, w1.x, acc); acc = fmaf(r1.y, w1.y, acc);
    acc = fmaf(r1.z, w1.z, acc); acc = fmaf(r1.w, w1.w, acc);
    float dt = (acc > 20.f) ? acc : __logf(1.f + __expf(acc));
    float xv = xssm[xbase + (size_t)l * 256];
    float zv = zb[xbase + (size_t)l * 256];
    float dtx = dt * xv;
    float y = 0.f;
    #pragma unroll
    for (int q = 0; q < 4; ++q) {
      float4 Bq = row[2 + q], Cq = row[6 + q];
      float bb4[4] = {Bq.x, Bq.y, Bq.z, Bq.w};
      float cc4[4] = {Cq.x, Cq.y, Cq.z, Cq.w};
      #pragma unroll
      for (int j = 0; j < 4; ++j) {
        int s = q * 4 + j;
        float dA = __expf(dt * Aneg[s]);
        h[s] = fmaf(dA, h[s], dtx * bb4[j]);
        y = fmaf(h[s], cc4[j], y);
      }
    }
    y = (y + Dd * xv) * siluf(zv);
    ybf[xbase + (size_t)l * 256] = f2bf(y);
  }
}

// ---------------- LayerNorm(128) + transpose to NCHW ------------------------
__global__ __launch_bounds__(256) void ln_transpose(
    const float* __restrict__ X,
    const float* __restrict__ g, const float* __restrict__ b,
    float* __restrict__ out)
{
  __shared__ float buf[64][129];
  const int t0 = blockIdx.x * 64;
  const int bb = t0 >> 12, l0 = t0 & 4095;
  const int tid = threadIdx.x;
  for (int idx = tid; idx < 64 * 128; idx += 256)
    buf[idx >> 7][idx & 127] = X[(size_t)t0 * 128 + idx];
  __syncthreads();
  const int tt = tid >> 2, q = tid & 3;
  float s = 0.f, sq = 0.f;
  #pragma unroll
  for (int i = 0; i < 32; ++i) {
    float v = buf[tt][q * 32 + i];
    s += v; sq += v * v;
  }
  s  += __shfl_xor(s, 1);  s  += __shfl_xor(s, 2);
  sq += __shfl_xor(sq, 1); sq += __shfl_xor(sq, 2);
  float mu = s * (1.f / 128.f);
  float var = sq * (1.f / 128.f) - mu * mu;
  float rstd = rsqrtf(fmaxf(var, 0.f) + 1e-5f);
  #pragma unroll
  for (int i = 0; i < 32; ++i) {
    int c = q * 32 + i;
    buf[tt][c] = (buf[tt][c] - mu) * rstd * g[c] + b[c];
  }
  __syncthreads();
  for (int idx = tid; idx < 64 * 128; idx += 256) {
    int c = idx >> 6, t2 = idx & 63;
    out[((size_t)bb * 128 + c) * 4096 + l0 + t2] = buf[t2][c];
  }
}

// ---------------------------------------------------------------------------
extern "C" void kernel_launch(void* const* d_in, const int* in_sizes, int n_in,
                              void* d_out, int out_size, void* d_ws, size_t ws_size,
                              hipStream_t stream) {
  const float* x        = (const float*)d_in[0];
  const float* conv1_w  = (const float*)d_in[1];
  const float* conv1_b  = (const float*)d_in[2];
  const float* bn1_g    = (const float*)d_in[3];
  const float* bn1_b    = (const float*)d_in[4];
  const float* bn1_m    = (const float*)d_in[5];
  const float* bn1_v    = (const float*)d_in[6];
  const float* conv2_w  = (const float*)d_in[7];
  const float* conv2_b  = (const float*)d_in[8];
  const float* bn2_g    = (const float*)d_in[9];
  const float* bn2_b    = (const float*)d_in[10];
  const float* bn2_m    = (const float*)d_in[11];
  const float* bn2_v    = (const float*)d_in[12];
  const float* in_proj_w  = (const float*)d_in[13];  // (512,128)
  const float* conv1d_w   = (const float*)d_in[14];  // (256,1,4)
  const float* conv1d_b   = (const float*)d_in[15];
  const float* x_proj_w   = (const float*)d_in[16];  // (40,256)
  const float* dt_proj_w  = (const float*)d_in[17];  // (256,8)
  const float* dt_proj_b  = (const float*)d_in[18];
  const float* A_log      = (const float*)d_in[19];  // (256,16)
  const float* Dp         = (const float*)d_in[20];  // (256)
  const float* out_proj_w = (const float*)d_in[21];  // (128,256)
  const float* ln_g       = (const float*)d_in[22];
  const float* ln_b       = (const float*)d_in[23];
  float* out = (float*)d_out;

  float* ws_f = (float*)d_ws;
  // workspace (float units), lifetime-reuse; peak ~31.1M f = 124.4 MB
  // region A [0, 8388608): xb (pre) -> xm (fp32) -> ybf [0,4194304) + outs
  unsigned short* xb   = (unsigned short*)ws_f;
  float*          xm   = ws_f;
  unsigned short* ybf  = (unsigned short*)ws_f;
  float*          outs = ws_f + 4194304;
  // region B: zb
  float*          zb   = ws_f + 8388608;
  // region C: xssm
  float*          xssm = ws_f + 16777216;
  // region D [25165824, 29360128): seqb+h1 (conv phase) -> Qbuf (scan phase)
  unsigned short* seqb = (unsigned short*)(ws_f + 25165824);
  unsigned short* h1   = (unsigned short*)(ws_f + 27262976);
  float*          Qbuf = ws_f + 25165824;   // 4,194,304 f = B*NC*256*16
  // region E/F/G
  float*          xdb  = ws_f + 29360128;   // 1,310,720 f
  float*          Sbuf = ws_f + 30670848;   //   262,144 f
  unsigned short* wb1  = (unsigned short*)(ws_f + 30932992);
  unsigned short* wb2  = (unsigned short*)(ws_f + 30969856);
  unsigned short* win  = (unsigned short*)(ws_f + 31043584);
  unsigned short* wout = (unsigned short*)(ws_f + 31076352);

  // pre-passes
  nchw2nhwc_bf16<<<512, 256, 0, stream>>>(x, xb);
  convw_prep<64><<<(73728 + 255) / 256, 256, 0, stream>>>(conv1_w, wb1);
  convw_prep<128><<<(147456 + 255) / 256, 256, 0, stream>>>(conv2_w, wb2);
  f32_to_bf16<<<256, 256, 0, stream>>>(in_proj_w, win, 65536);
  f32_to_bf16<<<128, 256, 0, stream>>>(out_proj_w, wout, 32768);

  // convs (MFMA, BN+ReLU fused, bf16 NHWC out)
  conv_mfma<64><<<dim3(64, 8), 256, 0, stream>>>(
      xb, wb1, conv1_b, bn1_g, bn1_b, bn1_m, bn1_v, h1);
  conv_mfma<128><<<dim3(64, 8), 256, 0, stream>>>(
      h1, wb2, conv2_b, bn2_g, bn2_b, bn2_m, bn2_v, seqb);

  // in_proj (one GEMM, N=512 -> xm | z)
  gemm_mfma<128, 0><<<dim3(512, 4), 256, 0, stream>>>(seqb, win, xm, zb);

  conv1d_silu<<<2048, 256, 0, stream>>>(xm, conv1d_w, conv1d_b, xssm);
  gemm_nt<<<dim3(512, 1), 256, 0, stream>>>(xssm, x_proj_w, xdb, 32768, 40, 256);

  scan_pass1<<<dim3(NC, 8), 256, 0, stream>>>(
      xssm, xdb, dt_proj_w, dt_proj_b, A_log, Qbuf, Sbuf);
  scan_combine<<<128, 256, 0, stream>>>(Qbuf, Sbuf, A_log);
  scan_pass2<<<dim3(NC, 8), 256, 0, stream>>>(
      xssm, xdb, zb, dt_proj_w, dt_proj_b, A_log, Dp, Qbuf, ybf);

  // out_proj (MFMA) + LN/transpose
  gemm_mfma<256, 1><<<dim3(512, 1), 256, 0, stream>>>(ybf, wout, outs, nullptr);
  ln_transpose<<<512, 256, 0, stream>>>(outs, ln_g, ln_b, out);
}